// Round 12
// baseline (197.750 us; speedup 1.0000x reference)
//
#include <hip/hip_runtime.h>
#include <hip/hip_bf16.h>

typedef unsigned short u16;
typedef unsigned int u32;
typedef __attribute__((ext_vector_type(4))) float f32x4;
typedef __attribute__((ext_vector_type(4))) u16 u16x4;
typedef __attribute__((ext_vector_type(8))) u16 u16x8;
typedef __attribute__((ext_vector_type(8))) short s16x8;

__device__ __forceinline__ u16 f2bf(float f) {
    union { float f; u32 u; } v; v.f = f;
    u32 r = v.u + 0x7FFFu + ((v.u >> 16) & 1u);
    return (u16)(r >> 16);
}

__device__ __forceinline__ void gl_lds16(const u16* g, u16* l) {
    __builtin_amdgcn_global_load_lds(
        (const __attribute__((address_space(1))) unsigned int*)(const void*)g,
        (__attribute__((address_space(3))) unsigned int*)(void*)l, 16, 0, 0);
}

// ---------------- fused prep: permc (8192 blocks) + permx (4096) + wtrans (256) ----------------
__global__ __launch_bounds__(256) void prep_kernel(
    const float* __restrict__ w0, const float* __restrict__ w1,
    const float* __restrict__ w2, const float* __restrict__ w3, u16* __restrict__ WT,
    const float* __restrict__ x, u16* __restrict__ Aq,
    const float* __restrict__ ctx, u16* __restrict__ Actx) {
    __shared__ char smem[16640];
    int bid = blockIdx.x;
    int tid = threadIdx.x;
    if (bid < 8192) {
        // ---- permc: context -> Actx (65536 x 512 bf16), tiled transpose ----
        u16 (*t)[68] = (u16(*)[68])smem;
        int b2 = bid;
        int cb = b2 & 7; b2 >>= 3;
        int xb = b2 & 1; b2 >>= 1;
        int y  = b2 & 127; b2 >>= 7;
        int b  = b2;
        long ibase = ((long)(b * 512 + cb * 64) * 128 + y) * 128 + xb * 64;
#pragma unroll
        for (int p = 0; p < 4; ++p) {
            int task = p * 256 + tid;
            int cc = task >> 4, xl = (task & 15) * 4;
            float4 v = *(const float4*)&ctx[ibase + (long)cc * 16384 + xl];
            u16x4 o = {f2bf(v.x), f2bf(v.y), f2bf(v.z), f2bf(v.w)};
            *(u16x4*)&t[cc][xl] = o;
        }
        __syncthreads();
#pragma unroll
        for (int p = 0; p < 2; ++p) {
            int task = p * 256 + tid;
            int xx = task >> 3, j = task & 7;
            u16x8 o;
#pragma unroll
            for (int i = 0; i < 8; ++i) o[i] = t[j * 8 + i][xx];
            int xg = xb * 64 + xx;
            int row = b * 16384 + (y >> 3) * 1024 + (xg >> 3) * 64 + (y & 7) * 8 + (xg & 7);
            *(u16x8*)&Actx[(long)row * 512 + cb * 64 + j * 8] = o;
        }
    } else if (bid < 12288) {
        // ---- permx: x -> Aq (16384 x 512 bf16), tiled transpose ----
        u16 (*t)[36] = (u16(*)[36])smem;
        int b2 = bid - 8192;
        int cb = b2 & 7; b2 >>= 3;
        int y  = b2 & 31; b2 >>= 5;
        int tt = b2 & 3; b2 >>= 2;
        int b  = b2;
        long ibase = ((long)(b * 512 + cb * 64) * 4 + tt) * 1024 + y * 32;
#pragma unroll
        for (int p = 0; p < 2; ++p) {
            int task = p * 256 + tid;
            int cc = task >> 3, xl = (task & 7) * 4;
            float4 v = *(const float4*)&x[ibase + (long)cc * 4096 + xl];
            u16x4 o = {f2bf(v.x), f2bf(v.y), f2bf(v.z), f2bf(v.w)};
            *(u16x4*)&t[cc][xl] = o;
        }
        __syncthreads();
        {
            int xx = tid >> 3, j = tid & 7;
            u16x8 o;
#pragma unroll
            for (int i = 0; i < 8; ++i) o[i] = t[j * 8 + i][xx];
            int row = b * 4096 + (y >> 1) * 256 + (xx >> 1) * 16 + tt * 4 + (y & 1) * 2 + (xx & 1);
            *(u16x8*)&Aq[(long)row * 512 + cb * 64 + j * 8] = o;
        }
    } else {
        // ---- wtrans: Wt[j][c] = W[c][j], f32 -> bf16 ----
        float (*t)[65] = (float(*)[65])smem;
        int b2 = bid - 12288;
        int wsel = b2 >> 6;
        int tile = b2 & 63;
        int j0 = (tile >> 3) * 64, c0 = (tile & 7) * 64;
        const float* src = wsel == 0 ? w0 : wsel == 1 ? w1 : wsel == 2 ? w2 : w3;
        u16* out = WT + (long)wsel * 512 * 512;
        int tj = tid & 63;
        int ti = tid >> 6;
#pragma unroll
        for (int p = 0; p < 16; ++p) {
            int row = p * 4 + ti;
            t[row][tj] = src[(long)(c0 + row) * 512 + j0 + tj];
        }
        __syncthreads();
#pragma unroll
        for (int p = 0; p < 16; ++p) {
            int jl = p * 4 + ti;
            out[(long)(j0 + jl) * 512 + c0 + tj] = f2bf(t[tj][jl]);
        }
    }
}

// ---------------- 128x128-tile bf16 GEMM (final proj), counted-vmcnt schedule ----------------
template <int FINAL>
__global__ __launch_bounds__(256, 2) void gemm128_kernel(
    const u16* __restrict__ A, const u16* __restrict__ Bt,
    u16* __restrict__ Cb, float* __restrict__ Cf, const float* __restrict__ bias) {
    __shared__ u16 As[2][8192];
    __shared__ u16 Bs[2][8192];
    int tid = threadIdx.x;
    int lane = tid & 63;
    int w = tid >> 6;
    int wm = w >> 1, wn = w & 1;
    int bid = blockIdx.x;
    int wg = (bid & 7) * 64 + (bid >> 3);   // grid 512, XCD chunk swizzle
    int m0 = (wg >> 2) * 128;
    int n0 = (wg & 3) * 128;

    const f32x4 z = {0.f, 0.f, 0.f, 0.f};
    f32x4 acc[4][4];
#pragma unroll
    for (int i = 0; i < 4; ++i)
#pragma unroll
        for (int j = 0; j < 4; ++j) acc[i][j] = z;

    int aoff[4], boff[4], lb[4];
#pragma unroll
    for (int i = 0; i < 4; ++i) {
        int s = i * 256 + tid;
        int row = s >> 3;
        int cb = (s & 7) ^ (row & 7);
        aoff[i] = (m0 + row) * 512 + cb * 8;
        boff[i] = (n0 + row) * 512 + cb * 8;
        lb[i] = (i * 256 + w * 64) * 8;
    }
    int la = lane & 15, lg = lane >> 4;

    // prologue: stage K-tiles 0 (buf0) and 1 (buf1)
#pragma unroll
    for (int i = 0; i < 4; ++i) {
        gl_lds16(&A[aoff[i]], &As[0][lb[i]]);
        gl_lds16(&Bt[boff[i]], &Bs[0][lb[i]]);
    }
#pragma unroll
    for (int i = 0; i < 4; ++i) {
        gl_lds16(&A[aoff[i] + 64], &As[1][lb[i]]);
        gl_lds16(&Bt[boff[i] + 64], &Bs[1][lb[i]]);
    }
    asm volatile("s_waitcnt vmcnt(8)" ::: "memory");   // tile0 landed; tile1 in flight
    __builtin_amdgcn_s_barrier();
    asm volatile("" ::: "memory");

#pragma unroll
    for (int t = 0; t < 8; ++t) {
        int buf = t & 1;
        const u16* Ab = As[buf];
        const u16* Bb = Bs[buf];
#pragma unroll
        for (int kk = 0; kk < 2; ++kk) {
            int cb = kk * 4 + lg;
            s16x8 af[4], bfr[4];
#pragma unroll
            for (int mt = 0; mt < 4; ++mt) {
                int r = wm * 64 + mt * 16 + la;
                af[mt] = *(const s16x8*)&Ab[r * 64 + ((cb ^ (r & 7)) * 8)];
            }
#pragma unroll
            for (int nt = 0; nt < 4; ++nt) {
                int c = wn * 64 + nt * 16 + la;
                bfr[nt] = *(const s16x8*)&Bb[c * 64 + ((cb ^ (c & 7)) * 8)];
            }
            __builtin_amdgcn_s_setprio(1);
#pragma unroll
            for (int mt = 0; mt < 4; ++mt)
#pragma unroll
                for (int nt = 0; nt < 4; ++nt)
                    acc[mt][nt] = __builtin_amdgcn_mfma_f32_16x16x32_bf16(af[mt], bfr[nt], acc[mt][nt], 0, 0, 0);
            __builtin_amdgcn_s_setprio(0);
        }
        if (t < 6) {
            asm volatile("" ::: "memory");
            __builtin_amdgcn_s_barrier();              // all waves done reading buf t&1
            int ko2 = (t + 2) * 64;
#pragma unroll
            for (int i = 0; i < 4; ++i) {
                gl_lds16(&A[aoff[i] + ko2], &As[buf][lb[i]]);
                gl_lds16(&Bt[boff[i] + ko2], &Bs[buf][lb[i]]);
            }
            asm volatile("s_waitcnt vmcnt(8)" ::: "memory");  // t+1 landed; t+2 in flight
            __builtin_amdgcn_s_barrier();              // publish tile t+1
            asm volatile("" ::: "memory");
        } else if (t == 6) {
            asm volatile("s_waitcnt vmcnt(0)" ::: "memory");  // drain: tile 7 landed
            __builtin_amdgcn_s_barrier();
            asm volatile("" ::: "memory");
        }
    }

#pragma unroll
    for (int mt = 0; mt < 4; ++mt) {
#pragma unroll
        for (int nt = 0; nt < 4; ++nt) {
            int col = n0 + wn * 64 + nt * 16 + la;
#pragma unroll
            for (int rr = 0; rr < 4; ++rr) {
                int r = m0 + wm * 64 + mt * 16 + lg * 4 + rr;
                float v = acc[mt][nt][rr];
                if (FINAL) {
                    int bb = r >> 12, hg = (r >> 8) & 15, wgx = (r >> 4) & 15;
                    int tt = (r >> 2) & 3, rr0 = (r >> 1) & 1, cc0 = r & 1;
                    int tok = bb * 4096 + tt * 1024 + (hg * 2 + rr0) * 32 + wgx * 2 + cc0;
                    Cf[(long)tok * 512 + col] = v + bias[col];
                } else {
                    Cb[(long)r * 512 + col] = f2bf(v);
                }
            }
        }
    }
}

// ---------------- fused K+V + Q GEMM: 256x256 tiles, 4-phase counted-vmcnt schedule ----------------
// Grid 1152 = 1024 KV-blocks + 128 Q-blocks (same shape 256^2 x K=512; fills the half-round
// that a separate gemmQ dispatch would waste, and removes one launch gap).
// wg < 1024: KV (A=Actx, B=WTk||WTv contiguous) -> CKV[65536][1024] interleaved.
// wg >= 1024: Q (A=Aq, B=WTq) -> CQ[16384][512].  Inner loop byte-identical for both.
__global__ __launch_bounds__(512, 2) void gemmkvq_kernel(
    const u16* __restrict__ Actx, const u16* __restrict__ Bkv,
    const u16* __restrict__ Aq, const u16* __restrict__ WTq,
    u16* __restrict__ CKV, u16* __restrict__ CQ) {
    __shared__ u16 lds[2][2][16384];   // [buf][A/B][256 rows x 64]
    int tid = threadIdx.x;
    int lane = tid & 63;
    int w = tid >> 6;                  // 0..7
    int wm = w >> 2, wn = w & 3;
    int la = lane & 15, lg = lane >> 4;
    int bid = blockIdx.x;
    int wg = (bid & 7) * 144 + (bid >> 3);   // grid 1152 (%8==0), XCD chunk swizzle

    const u16 *sA, *sB;
    u16* Co;
    int m0, n0, cstride;
    if (wg < 1024) {
        m0 = (wg >> 2) * 256;
        n0 = (wg & 3) * 256;
        sA = Actx; sB = Bkv; Co = CKV; cstride = 1024;
    } else {
        int q = wg - 1024;             // 0..127: 64 m-tiles x 2 n-tiles
        m0 = (q >> 1) * 256;
        n0 = (q & 1) * 256;
        sA = Aq; sB = WTq; Co = CQ; cstride = 512;
    }

    const f32x4 z = {0.f, 0.f, 0.f, 0.f};
    f32x4 acc[8][4];
#pragma unroll
    for (int i = 0; i < 8; ++i)
#pragma unroll
        for (int j = 0; j < 4; ++j) acc[i][j] = z;

    int aoff[4], boff[4], lsl[4];
#pragma unroll
    for (int i = 0; i < 4; ++i) {
        int s = i * 512 + tid;
        int row = s >> 3;              // slot i covers rows [64i, 64i+64)
        int cb = (s & 7) ^ (row & 7);
        aoff[i] = (m0 + row) * 512 + cb * 8;
        boff[i] = (n0 + row) * 512 + cb * 8;
        lsl[i] = (i * 512 + w * 64) * 8;
    }

    s16x8 bfr[4][2];                   // B fragments, cached across the whole K-tile

    // prologue: stage tiles 0 (buf0) and 1 (buf1)
#pragma unroll
    for (int i = 0; i < 4; ++i) {
        gl_lds16(&sA[aoff[i]], &lds[0][0][lsl[i]]);
        gl_lds16(&sB[boff[i]], &lds[0][1][lsl[i]]);
    }
#pragma unroll
    for (int i = 0; i < 4; ++i) {
        gl_lds16(&sA[aoff[i] + 64], &lds[1][0][lsl[i]]);
        gl_lds16(&sB[boff[i] + 64], &lds[1][1][lsl[i]]);
    }
    asm volatile("s_waitcnt vmcnt(8)" ::: "memory");   // tile0 landed; tile1 in flight
    __builtin_amdgcn_s_barrier();
    asm volatile("" ::: "memory");

#pragma unroll
    for (int t = 0; t < 8; ++t) {
        int buf = t & 1;
        const u16* Ab = lds[buf][0];
        const u16* Bb = lds[buf][1];
        int ko2 = (t + 2) * 64;

        // ---- P1: (mh=0, kk=0), load B frags kk=0 ----
        {
            int cb = lg;
            s16x8 af[4];
#pragma unroll
            for (int mt = 0; mt < 4; ++mt) {
                int r = wm * 128 + mt * 16 + la;
                af[mt] = *(const s16x8*)&Ab[r * 64 + ((cb ^ (r & 7)) * 8)];
            }
#pragma unroll
            for (int nt = 0; nt < 4; ++nt) {
                int c = wn * 64 + nt * 16 + la;
                bfr[nt][0] = *(const s16x8*)&Bb[c * 64 + ((cb ^ (c & 7)) * 8)];
            }
            __builtin_amdgcn_s_barrier();
            __builtin_amdgcn_s_setprio(1);
#pragma unroll
            for (int mt = 0; mt < 4; ++mt)
#pragma unroll
                for (int nt = 0; nt < 4; ++nt)
                    acc[mt][nt] = __builtin_amdgcn_mfma_f32_16x16x32_bf16(af[mt], bfr[nt][0], acc[mt][nt], 0, 0, 0);
            __builtin_amdgcn_s_setprio(0);
            __builtin_amdgcn_sched_barrier(0);
            __builtin_amdgcn_s_barrier();
        }
        // ---- P2: (mh=0, kk=1), load B frags kk=1 ----
        {
            int cb = 4 + lg;
            s16x8 af[4];
#pragma unroll
            for (int mt = 0; mt < 4; ++mt) {
                int r = wm * 128 + mt * 16 + la;
                af[mt] = *(const s16x8*)&Ab[r * 64 + ((cb ^ (r & 7)) * 8)];
            }
#pragma unroll
            for (int nt = 0; nt < 4; ++nt) {
                int c = wn * 64 + nt * 16 + la;
                bfr[nt][1] = *(const s16x8*)&Bb[c * 64 + ((cb ^ (c & 7)) * 8)];
            }
            __builtin_amdgcn_s_barrier();
            __builtin_amdgcn_s_setprio(1);
#pragma unroll
            for (int mt = 0; mt < 4; ++mt)
#pragma unroll
                for (int nt = 0; nt < 4; ++nt)
                    acc[mt][nt] = __builtin_amdgcn_mfma_f32_16x16x32_bf16(af[mt], bfr[nt][1], acc[mt][nt], 0, 0, 0);
            __builtin_amdgcn_s_setprio(0);
            __builtin_amdgcn_sched_barrier(0);
            __builtin_amdgcn_s_barrier();
            // B tile + A slots 0,2 now fully consumed by all waves
        }
        // ---- P3: (mh=1, kk=1), B frags reused; stage B slots 0,1 + A slot 0 of t+2 ----
        {
            int cb = 4 + lg;
            s16x8 af[4];
#pragma unroll
            for (int mt = 0; mt < 4; ++mt) {
                int r = wm * 128 + 64 + mt * 16 + la;
                af[mt] = *(const s16x8*)&Ab[r * 64 + ((cb ^ (r & 7)) * 8)];
            }
            if (t < 6) {
                gl_lds16(&sB[boff[0] + ko2], &lds[buf][1][lsl[0]]);
                gl_lds16(&sB[boff[1] + ko2], &lds[buf][1][lsl[1]]);
                gl_lds16(&sA[aoff[0] + ko2], &lds[buf][0][lsl[0]]);
            }
            __builtin_amdgcn_s_barrier();
            __builtin_amdgcn_s_setprio(1);
#pragma unroll
            for (int mt = 0; mt < 4; ++mt)
#pragma unroll
                for (int nt = 0; nt < 4; ++nt)
                    acc[4 + mt][nt] = __builtin_amdgcn_mfma_f32_16x16x32_bf16(af[mt], bfr[nt][1], acc[4 + mt][nt], 0, 0, 0);
            __builtin_amdgcn_s_setprio(0);
            __builtin_amdgcn_sched_barrier(0);
            __builtin_amdgcn_s_barrier();
        }
        // ---- P4: (mh=1, kk=0), B frags reused; stage B slots 2,3 + A slot 2 of t+2 ----
        {
            int cb = lg;
            s16x8 af[4];
#pragma unroll
            for (int mt = 0; mt < 4; ++mt) {
                int r = wm * 128 + 64 + mt * 16 + la;
                af[mt] = *(const s16x8*)&Ab[r * 64 + ((cb ^ (r & 7)) * 8)];
            }
            if (t < 6) {
                gl_lds16(&sB[boff[2] + ko2], &lds[buf][1][lsl[2]]);
                gl_lds16(&sB[boff[3] + ko2], &lds[buf][1][lsl[3]]);
                gl_lds16(&sA[aoff[2] + ko2], &lds[buf][0][lsl[2]]);
            }
            __builtin_amdgcn_s_barrier();
            __builtin_amdgcn_s_setprio(1);
#pragma unroll
            for (int mt = 0; mt < 4; ++mt)
#pragma unroll
                for (int nt = 0; nt < 4; ++nt)
                    acc[4 + mt][nt] = __builtin_amdgcn_mfma_f32_16x16x32_bf16(af[mt], bfr[nt][0], acc[4 + mt][nt], 0, 0, 0);
            __builtin_amdgcn_s_setprio(0);
            __builtin_amdgcn_sched_barrier(0);
            __builtin_amdgcn_s_barrier();
            // A slots 1,3 (mh=1 rows) now fully consumed
        }
        // ---- tile end: finish stage of t+2, counted wait, publish t+1 ----
        if (t < 6) {
            gl_lds16(&sA[aoff[1] + ko2], &lds[buf][0][lsl[1]]);
            gl_lds16(&sA[aoff[3] + ko2], &lds[buf][0][lsl[3]]);
            asm volatile("s_waitcnt vmcnt(8)" ::: "memory");   // t+1 landed; t+2 in flight
            __builtin_amdgcn_s_barrier();
            asm volatile("" ::: "memory");
        } else if (t == 6) {
            asm volatile("s_waitcnt vmcnt(0)" ::: "memory");   // drain: tile 7 landed
            __builtin_amdgcn_s_barrier();
            asm volatile("" ::: "memory");
        }
    }

#pragma unroll
    for (int mt = 0; mt < 8; ++mt) {
#pragma unroll
        for (int nt = 0; nt < 4; ++nt) {
            int col = n0 + wn * 64 + nt * 16 + la;
#pragma unroll
            for (int rr = 0; rr < 4; ++rr) {
                int r = m0 + wm * 128 + mt * 16 + lg * 4 + rr;
                Co[(long)r * cstride + col] = f2bf(acc[mt][nt][rr]);
            }
        }
    }
}

// ---------------- windowed attention: 4 waves/block, KV interleaved [win][kv][1024] ----------------
// V consumed via per-wave LDS transpose: cooperative 16B row loads issued BEFORE QK^T
// (HBM latency hides under MFMAs), parked in a wave-private [64][70] slice (pad 70 ->
// column reads spread banks, conflict-free), PV reads 64 ds_read_u16.
__global__ __launch_bounds__(256) void attn_kernel(
    const u16* __restrict__ Q, const u16* __restrict__ KV, u16* __restrict__ O) {
    __shared__ u16 Vls[4][64][70];
    __shared__ u16 P[4][16 * 104];
    int bid = blockIdx.x;
    int wgid = (bid & 7) * 256 + (bid >> 3);  // grid 2048, XCD chunk swizzle
    int tid = threadIdx.x;
    int wid = tid >> 6;
    int lane = tid & 63;
    int win = wgid >> 1;
    int h = (wgid & 1) * 4 + wid;
    int la = lane & 15, lg = lane >> 4;
    u16* Pw = P[wid];
    const u16* Qb = Q + (long)win * 16 * 512 + h * 64;
    const u16* Kb = KV + (long)win * 64 * 1024 + h * 64;
    const u16* Vb = KV + (long)win * 64 * 1024 + 512 + h * 64;

    // V tile -> wave-private LDS slice (issue early; latency hides under QK^T)
    {
        int rsel = lane >> 3;          // 8 rows per iteration
        int dsel = (lane & 7) * 8;     // 8 lanes cover one 128B row
#pragma unroll
        for (int i = 0; i < 8; ++i) {
            int kv = i * 8 + rsel;
            s16x8 v = *(const s16x8*)&Vb[(long)kv * 1024 + dsel];
            *(s16x8*)&Vls[wid][kv][dsel] = v;
        }
    }

    s16x8 qf[2];
#pragma unroll
    for (int kk = 0; kk < 2; ++kk)
        qf[kk] = *(const s16x8*)&Qb[la * 512 + kk * 32 + lg * 8];

    const f32x4 z = {0.f, 0.f, 0.f, 0.f};
    f32x4 st[4];
#pragma unroll
    for (int rt = 0; rt < 4; ++rt) st[rt] = z;
#pragma unroll
    for (int rt = 0; rt < 4; ++rt)
#pragma unroll
        for (int kk = 0; kk < 2; ++kk) {
            s16x8 kf = *(const s16x8*)&Kb[(rt * 16 + la) * 1024 + kk * 32 + lg * 8];
            st[rt] = __builtin_amdgcn_mfma_f32_16x16x32_bf16(kf, qf[kk], st[rt], 0, 0, 0);
        }
    float mloc = -1e30f;
#pragma unroll
    for (int rt = 0; rt < 4; ++rt)
#pragma unroll
        for (int rr = 0; rr < 4; ++rr) {
            st[rt][rr] *= 0.125f;
            mloc = fmaxf(mloc, st[rt][rr]);
        }
    mloc = fmaxf(mloc, __shfl_xor(mloc, 16));
    mloc = fmaxf(mloc, __shfl_xor(mloc, 32));
    float p[4][4];
    float sloc = 0.f;
#pragma unroll
    for (int rt = 0; rt < 4; ++rt)
#pragma unroll
        for (int rr = 0; rr < 4; ++rr) {
            p[rt][rr] = __expf(st[rt][rr] - mloc);
            sloc += p[rt][rr];
        }
    sloc += __shfl_xor(sloc, 16);
    sloc += __shfl_xor(sloc, 32);
    float inv = 1.0f / sloc;
#pragma unroll
    for (int rt = 0; rt < 4; ++rt)
#pragma unroll
        for (int rr = 0; rr < 4; ++rr)
            Pw[la * 104 + rt * 16 + lg * 4 + rr] = f2bf(p[rt][rr] * inv);
    __syncthreads();

    f32x4 od[4];
#pragma unroll
    for (int dt = 0; dt < 4; ++dt) od[dt] = z;
#pragma unroll
    for (int kk2 = 0; kk2 < 2; ++kk2) {
        s16x8 pa = *(const s16x8*)&Pw[la * 104 + kk2 * 32 + lg * 8];
#pragma unroll
        for (int dt = 0; dt < 4; ++dt) {
            s16x8 vb;
#pragma unroll
            for (int j = 0; j < 8; ++j)
                vb[j] = (short)Vls[wid][kk2 * 32 + lg * 8 + j][dt * 16 + la];
            od[dt] = __builtin_amdgcn_mfma_f32_16x16x32_bf16(pa, vb, od[dt], 0, 0, 0);
        }
    }
    u16* Ob = O + (long)win * 16 * 512 + h * 64;
#pragma unroll
    for (int dt = 0; dt < 4; ++dt)
#pragma unroll
        for (int rr = 0; rr < 4; ++rr)
            Ob[(long)(lg * 4 + rr) * 512 + dt * 16 + la] = f2bf(od[dt][rr]);
}

__global__ void sentinel_kernel(float* out) {
    if (threadIdx.x == 0 && blockIdx.x == 0) out[0] = -12345.0f;
}

extern "C" void kernel_launch(void* const* d_in, const int* in_sizes, int n_in,
                              void* d_out, int out_size, void* d_ws, size_t ws_size,
                              hipStream_t stream) {
    const float* x   = (const float*)d_in[0];
    const float* ctx = (const float*)d_in[1];
    const float* Wq  = (const float*)d_in[2];
    const float* Wk  = (const float*)d_in[3];
    const float* Wv  = (const float*)d_in[4];
    const float* Wo  = (const float*)d_in[5];
    const float* bo  = (const float*)d_in[6];
    float* out = (float*)d_out;

    u16* wsb  = (u16*)d_ws;
    u16* WT   = wsb;                    // 4 * 512*512 (q, k, v, o transposed)
    u16* Aq   = WT + 4l * 262144;       // 16384*512
    u16* Actx = Aq + 8388608l;          // 65536*512
    u16* Qb   = Actx + 33554432l;       // 16384*512
    u16* KVb  = Qb + 8388608l;          // 65536*1024 (K cols 0..511, V cols 512..1023)
    u16* Ob   = KVb + 67108864l;        // 16384*512
    size_t need = (size_t)(126877696l) * 2;
    if (ws_size < need) {
        sentinel_kernel<<<1, 64, 0, stream>>>(out);
        return;
    }

    prep_kernel<<<12544, 256, 0, stream>>>(Wq, Wk, Wv, Wo, WT, x, Aq, ctx, Actx);
    gemmkvq_kernel<<<1152, 512, 0, stream>>>(Actx, WT + 262144l, Aq, WT, KVb, Qb);
    attn_kernel<<<2048, 256, 0, stream>>>(Qb, KVb, Ob);
    gemm128_kernel<1><<<512, 256, 0, stream>>>(Ob, WT + 3l * 262144, nullptr, out, bo);
}

// Round 13
// 193.888 us; speedup vs baseline: 1.0199x; 1.0199x over previous
//
#include <hip/hip_runtime.h>
#include <hip/hip_bf16.h>

typedef unsigned short u16;
typedef unsigned int u32;
typedef __attribute__((ext_vector_type(4))) float f32x4;
typedef __attribute__((ext_vector_type(4))) u16 u16x4;
typedef __attribute__((ext_vector_type(8))) u16 u16x8;
typedef __attribute__((ext_vector_type(8))) short s16x8;

__device__ __forceinline__ u16 f2bf(float f) {
    union { float f; u32 u; } v; v.f = f;
    u32 r = v.u + 0x7FFFu + ((v.u >> 16) & 1u);
    return (u16)(r >> 16);
}

__device__ __forceinline__ void gl_lds16(const u16* g, u16* l) {
    __builtin_amdgcn_global_load_lds(
        (const __attribute__((address_space(1))) unsigned int*)(const void*)g,
        (__attribute__((address_space(3))) unsigned int*)(void*)l, 16, 0, 0);
}

// ---------------- fused prep: permc (8192 blocks) + permx (4096) + wtrans (256) ----------------
__global__ __launch_bounds__(256) void prep_kernel(
    const float* __restrict__ w0, const float* __restrict__ w1,
    const float* __restrict__ w2, const float* __restrict__ w3, u16* __restrict__ WT,
    const float* __restrict__ x, u16* __restrict__ Aq,
    const float* __restrict__ ctx, u16* __restrict__ Actx) {
    __shared__ char smem[16640];
    int bid = blockIdx.x;
    int tid = threadIdx.x;
    if (bid < 8192) {
        // ---- permc: context -> Actx (65536 x 512 bf16), tiled transpose ----
        u16 (*t)[68] = (u16(*)[68])smem;
        int b2 = bid;
        int cb = b2 & 7; b2 >>= 3;
        int xb = b2 & 1; b2 >>= 1;
        int y  = b2 & 127; b2 >>= 7;
        int b  = b2;
        long ibase = ((long)(b * 512 + cb * 64) * 128 + y) * 128 + xb * 64;
#pragma unroll
        for (int p = 0; p < 4; ++p) {
            int task = p * 256 + tid;
            int cc = task >> 4, xl = (task & 15) * 4;
            float4 v = *(const float4*)&ctx[ibase + (long)cc * 16384 + xl];
            u16x4 o = {f2bf(v.x), f2bf(v.y), f2bf(v.z), f2bf(v.w)};
            *(u16x4*)&t[cc][xl] = o;
        }
        __syncthreads();
#pragma unroll
        for (int p = 0; p < 2; ++p) {
            int task = p * 256 + tid;
            int xx = task >> 3, j = task & 7;
            u16x8 o;
#pragma unroll
            for (int i = 0; i < 8; ++i) o[i] = t[j * 8 + i][xx];
            int xg = xb * 64 + xx;
            int row = b * 16384 + (y >> 3) * 1024 + (xg >> 3) * 64 + (y & 7) * 8 + (xg & 7);
            *(u16x8*)&Actx[(long)row * 512 + cb * 64 + j * 8] = o;
        }
    } else if (bid < 12288) {
        // ---- permx: x -> Aq (16384 x 512 bf16), tiled transpose ----
        u16 (*t)[36] = (u16(*)[36])smem;
        int b2 = bid - 8192;
        int cb = b2 & 7; b2 >>= 3;
        int y  = b2 & 31; b2 >>= 5;
        int tt = b2 & 3; b2 >>= 2;
        int b  = b2;
        long ibase = ((long)(b * 512 + cb * 64) * 4 + tt) * 1024 + y * 32;
#pragma unroll
        for (int p = 0; p < 2; ++p) {
            int task = p * 256 + tid;
            int cc = task >> 3, xl = (task & 7) * 4;
            float4 v = *(const float4*)&x[ibase + (long)cc * 4096 + xl];
            u16x4 o = {f2bf(v.x), f2bf(v.y), f2bf(v.z), f2bf(v.w)};
            *(u16x4*)&t[cc][xl] = o;
        }
        __syncthreads();
        {
            int xx = tid >> 3, j = tid & 7;
            u16x8 o;
#pragma unroll
            for (int i = 0; i < 8; ++i) o[i] = t[j * 8 + i][xx];
            int row = b * 4096 + (y >> 1) * 256 + (xx >> 1) * 16 + tt * 4 + (y & 1) * 2 + (xx & 1);
            *(u16x8*)&Aq[(long)row * 512 + cb * 64 + j * 8] = o;
        }
    } else {
        // ---- wtrans: Wt[j][c] = W[c][j], f32 -> bf16 ----
        float (*t)[65] = (float(*)[65])smem;
        int b2 = bid - 12288;
        int wsel = b2 >> 6;
        int tile = b2 & 63;
        int j0 = (tile >> 3) * 64, c0 = (tile & 7) * 64;
        const float* src = wsel == 0 ? w0 : wsel == 1 ? w1 : wsel == 2 ? w2 : w3;
        u16* out = WT + (long)wsel * 512 * 512;
        int tj = tid & 63;
        int ti = tid >> 6;
#pragma unroll
        for (int p = 0; p < 16; ++p) {
            int row = p * 4 + ti;
            t[row][tj] = src[(long)(c0 + row) * 512 + j0 + tj];
        }
        __syncthreads();
#pragma unroll
        for (int p = 0; p < 16; ++p) {
            int jl = p * 4 + ti;
            out[(long)(j0 + jl) * 512 + c0 + tj] = f2bf(t[tj][jl]);
        }
    }
}

// ---------------- 128x128-tile bf16 GEMM (final proj), counted-vmcnt schedule ----------------
template <int FINAL>
__global__ __launch_bounds__(256, 2) void gemm128_kernel(
    const u16* __restrict__ A, const u16* __restrict__ Bt,
    u16* __restrict__ Cb, float* __restrict__ Cf, const float* __restrict__ bias) {
    __shared__ u16 As[2][8192];
    __shared__ u16 Bs[2][8192];
    int tid = threadIdx.x;
    int lane = tid & 63;
    int w = tid >> 6;
    int wm = w >> 1, wn = w & 1;
    int bid = blockIdx.x;
    int wg = (bid & 7) * 64 + (bid >> 3);   // grid 512, XCD chunk swizzle
    int m0 = (wg >> 2) * 128;
    int n0 = (wg & 3) * 128;

    const f32x4 z = {0.f, 0.f, 0.f, 0.f};
    f32x4 acc[4][4];
#pragma unroll
    for (int i = 0; i < 4; ++i)
#pragma unroll
        for (int j = 0; j < 4; ++j) acc[i][j] = z;

    int aoff[4], boff[4], lb[4];
#pragma unroll
    for (int i = 0; i < 4; ++i) {
        int s = i * 256 + tid;
        int row = s >> 3;
        int cb = (s & 7) ^ (row & 7);
        aoff[i] = (m0 + row) * 512 + cb * 8;
        boff[i] = (n0 + row) * 512 + cb * 8;
        lb[i] = (i * 256 + w * 64) * 8;
    }
    int la = lane & 15, lg = lane >> 4;

    // prologue: stage K-tiles 0 (buf0) and 1 (buf1)
#pragma unroll
    for (int i = 0; i < 4; ++i) {
        gl_lds16(&A[aoff[i]], &As[0][lb[i]]);
        gl_lds16(&Bt[boff[i]], &Bs[0][lb[i]]);
    }
#pragma unroll
    for (int i = 0; i < 4; ++i) {
        gl_lds16(&A[aoff[i] + 64], &As[1][lb[i]]);
        gl_lds16(&Bt[boff[i] + 64], &Bs[1][lb[i]]);
    }
    asm volatile("s_waitcnt vmcnt(8)" ::: "memory");   // tile0 landed; tile1 in flight
    __builtin_amdgcn_s_barrier();
    asm volatile("" ::: "memory");

#pragma unroll
    for (int t = 0; t < 8; ++t) {
        int buf = t & 1;
        const u16* Ab = As[buf];
        const u16* Bb = Bs[buf];
#pragma unroll
        for (int kk = 0; kk < 2; ++kk) {
            int cb = kk * 4 + lg;
            s16x8 af[4], bfr[4];
#pragma unroll
            for (int mt = 0; mt < 4; ++mt) {
                int r = wm * 64 + mt * 16 + la;
                af[mt] = *(const s16x8*)&Ab[r * 64 + ((cb ^ (r & 7)) * 8)];
            }
#pragma unroll
            for (int nt = 0; nt < 4; ++nt) {
                int c = wn * 64 + nt * 16 + la;
                bfr[nt] = *(const s16x8*)&Bb[c * 64 + ((cb ^ (c & 7)) * 8)];
            }
            __builtin_amdgcn_s_setprio(1);
#pragma unroll
            for (int mt = 0; mt < 4; ++mt)
#pragma unroll
                for (int nt = 0; nt < 4; ++nt)
                    acc[mt][nt] = __builtin_amdgcn_mfma_f32_16x16x32_bf16(af[mt], bfr[nt], acc[mt][nt], 0, 0, 0);
            __builtin_amdgcn_s_setprio(0);
        }
        if (t < 6) {
            asm volatile("" ::: "memory");
            __builtin_amdgcn_s_barrier();              // all waves done reading buf t&1
            int ko2 = (t + 2) * 64;
#pragma unroll
            for (int i = 0; i < 4; ++i) {
                gl_lds16(&A[aoff[i] + ko2], &As[buf][lb[i]]);
                gl_lds16(&Bt[boff[i] + ko2], &Bs[buf][lb[i]]);
            }
            asm volatile("s_waitcnt vmcnt(8)" ::: "memory");  // t+1 landed; t+2 in flight
            __builtin_amdgcn_s_barrier();              // publish tile t+1
            asm volatile("" ::: "memory");
        } else if (t == 6) {
            asm volatile("s_waitcnt vmcnt(0)" ::: "memory");  // drain: tile 7 landed
            __builtin_amdgcn_s_barrier();
            asm volatile("" ::: "memory");
        }
    }

#pragma unroll
    for (int mt = 0; mt < 4; ++mt) {
#pragma unroll
        for (int nt = 0; nt < 4; ++nt) {
            int col = n0 + wn * 64 + nt * 16 + la;
#pragma unroll
            for (int rr = 0; rr < 4; ++rr) {
                int r = m0 + wm * 64 + mt * 16 + lg * 4 + rr;
                float v = acc[mt][nt][rr];
                if (FINAL) {
                    int bb = r >> 12, hg = (r >> 8) & 15, wgx = (r >> 4) & 15;
                    int tt = (r >> 2) & 3, rr0 = (r >> 1) & 1, cc0 = r & 1;
                    int tok = bb * 4096 + tt * 1024 + (hg * 2 + rr0) * 32 + wgx * 2 + cc0;
                    Cf[(long)tok * 512 + col] = v + bias[col];
                } else {
                    Cb[(long)r * 512 + col] = f2bf(v);
                }
            }
        }
    }
}

// ---------------- fused K+V + Q GEMM: 256x256 tiles, 4-phase counted-vmcnt schedule ----------------
// Grid 1152 = 1024 KV-blocks + 128 Q-blocks.  Per-XCD balanced mapping: xcd=bid&7,
// loc=bid>>3; loc<128 -> KV with wg=xcd*128+loc (BYTE-IDENTICAL to the r11-proven gemmkv
// swizzle: each XCD gets 32 contiguous token tiles x 4 roles); loc>=128 -> Q with
// qi=xcd*16+(loc-128) (each XCD gets exactly 16 of 128 Q-blocks; Q-blocks are the last
// 128 bids -> one uniform tail round on all XCDs).  Fixes r12's imbalance where XCD 7
// ran ALL 128 Q-blocks (+7us tail).
__global__ __launch_bounds__(512, 2) void gemmkvq_kernel(
    const u16* __restrict__ Actx, const u16* __restrict__ Bkv,
    const u16* __restrict__ Aq, const u16* __restrict__ WTq,
    u16* __restrict__ CKV, u16* __restrict__ CQ) {
    __shared__ u16 lds[2][2][16384];   // [buf][A/B][256 rows x 64]
    int tid = threadIdx.x;
    int lane = tid & 63;
    int w = tid >> 6;                  // 0..7
    int wm = w >> 2, wn = w & 3;
    int la = lane & 15, lg = lane >> 4;
    int bid = blockIdx.x;
    int xcd = bid & 7;
    int loc = bid >> 3;                // 0..143

    const u16 *sA, *sB;
    u16* Co;
    int m0, n0, cstride;
    if (loc < 128) {
        int wg = xcd * 128 + loc;      // r11-proven KV mapping
        m0 = (wg >> 2) * 256;
        n0 = (wg & 3) * 256;
        sA = Actx; sB = Bkv; Co = CKV; cstride = 1024;
    } else {
        int q = xcd * 16 + (loc - 128);   // 0..127: 64 m-tiles x 2 n-tiles, XCD-balanced
        m0 = (q >> 1) * 256;
        n0 = (q & 1) * 256;
        sA = Aq; sB = WTq; Co = CQ; cstride = 512;
    }

    const f32x4 z = {0.f, 0.f, 0.f, 0.f};
    f32x4 acc[8][4];
#pragma unroll
    for (int i = 0; i < 8; ++i)
#pragma unroll
        for (int j = 0; j < 4; ++j) acc[i][j] = z;

    int aoff[4], boff[4], lsl[4];
#pragma unroll
    for (int i = 0; i < 4; ++i) {
        int s = i * 512 + tid;
        int row = s >> 3;              // slot i covers rows [64i, 64i+64)
        int cb = (s & 7) ^ (row & 7);
        aoff[i] = (m0 + row) * 512 + cb * 8;
        boff[i] = (n0 + row) * 512 + cb * 8;
        lsl[i] = (i * 512 + w * 64) * 8;
    }

    s16x8 bfr[4][2];                   // B fragments, cached across the whole K-tile

    // prologue: stage tiles 0 (buf0) and 1 (buf1)
#pragma unroll
    for (int i = 0; i < 4; ++i) {
        gl_lds16(&sA[aoff[i]], &lds[0][0][lsl[i]]);
        gl_lds16(&sB[boff[i]], &lds[0][1][lsl[i]]);
    }
#pragma unroll
    for (int i = 0; i < 4; ++i) {
        gl_lds16(&sA[aoff[i] + 64], &lds[1][0][lsl[i]]);
        gl_lds16(&sB[boff[i] + 64], &lds[1][1][lsl[i]]);
    }
    asm volatile("s_waitcnt vmcnt(8)" ::: "memory");   // tile0 landed; tile1 in flight
    __builtin_amdgcn_s_barrier();
    asm volatile("" ::: "memory");

#pragma unroll
    for (int t = 0; t < 8; ++t) {
        int buf = t & 1;
        const u16* Ab = lds[buf][0];
        const u16* Bb = lds[buf][1];
        int ko2 = (t + 2) * 64;

        // ---- P1: (mh=0, kk=0), load B frags kk=0 ----
        {
            int cb = lg;
            s16x8 af[4];
#pragma unroll
            for (int mt = 0; mt < 4; ++mt) {
                int r = wm * 128 + mt * 16 + la;
                af[mt] = *(const s16x8*)&Ab[r * 64 + ((cb ^ (r & 7)) * 8)];
            }
#pragma unroll
            for (int nt = 0; nt < 4; ++nt) {
                int c = wn * 64 + nt * 16 + la;
                bfr[nt][0] = *(const s16x8*)&Bb[c * 64 + ((cb ^ (c & 7)) * 8)];
            }
            __builtin_amdgcn_s_barrier();
            __builtin_amdgcn_s_setprio(1);
#pragma unroll
            for (int mt = 0; mt < 4; ++mt)
#pragma unroll
                for (int nt = 0; nt < 4; ++nt)
                    acc[mt][nt] = __builtin_amdgcn_mfma_f32_16x16x32_bf16(af[mt], bfr[nt][0], acc[mt][nt], 0, 0, 0);
            __builtin_amdgcn_s_setprio(0);
            __builtin_amdgcn_sched_barrier(0);
            __builtin_amdgcn_s_barrier();
        }
        // ---- P2: (mh=0, kk=1), load B frags kk=1 ----
        {
            int cb = 4 + lg;
            s16x8 af[4];
#pragma unroll
            for (int mt = 0; mt < 4; ++mt) {
                int r = wm * 128 + mt * 16 + la;
                af[mt] = *(const s16x8*)&Ab[r * 64 + ((cb ^ (r & 7)) * 8)];
            }
#pragma unroll
            for (int nt = 0; nt < 4; ++nt) {
                int c = wn * 64 + nt * 16 + la;
                bfr[nt][1] = *(const s16x8*)&Bb[c * 64 + ((cb ^ (c & 7)) * 8)];
            }
            __builtin_amdgcn_s_barrier();
            __builtin_amdgcn_s_setprio(1);
#pragma unroll
            for (int mt = 0; mt < 4; ++mt)
#pragma unroll
                for (int nt = 0; nt < 4; ++nt)
                    acc[mt][nt] = __builtin_amdgcn_mfma_f32_16x16x32_bf16(af[mt], bfr[nt][1], acc[mt][nt], 0, 0, 0);
            __builtin_amdgcn_s_setprio(0);
            __builtin_amdgcn_sched_barrier(0);
            __builtin_amdgcn_s_barrier();
            // B tile + A slots 0,2 now fully consumed by all waves
        }
        // ---- P3: (mh=1, kk=1), B frags reused; stage B slots 0,1 + A slot 0 of t+2 ----
        {
            int cb = 4 + lg;
            s16x8 af[4];
#pragma unroll
            for (int mt = 0; mt < 4; ++mt) {
                int r = wm * 128 + 64 + mt * 16 + la;
                af[mt] = *(const s16x8*)&Ab[r * 64 + ((cb ^ (r & 7)) * 8)];
            }
            if (t < 6) {
                gl_lds16(&sB[boff[0] + ko2], &lds[buf][1][lsl[0]]);
                gl_lds16(&sB[boff[1] + ko2], &lds[buf][1][lsl[1]]);
                gl_lds16(&sA[aoff[0] + ko2], &lds[buf][0][lsl[0]]);
            }
            __builtin_amdgcn_s_barrier();
            __builtin_amdgcn_s_setprio(1);
#pragma unroll
            for (int mt = 0; mt < 4; ++mt)
#pragma unroll
                for (int nt = 0; nt < 4; ++nt)
                    acc[4 + mt][nt] = __builtin_amdgcn_mfma_f32_16x16x32_bf16(af[mt], bfr[nt][1], acc[4 + mt][nt], 0, 0, 0);
            __builtin_amdgcn_s_setprio(0);
            __builtin_amdgcn_sched_barrier(0);
            __builtin_amdgcn_s_barrier();
        }
        // ---- P4: (mh=1, kk=0), B frags reused; stage B slots 2,3 + A slot 2 of t+2 ----
        {
            int cb = lg;
            s16x8 af[4];
#pragma unroll
            for (int mt = 0; mt < 4; ++mt) {
                int r = wm * 128 + 64 + mt * 16 + la;
                af[mt] = *(const s16x8*)&Ab[r * 64 + ((cb ^ (r & 7)) * 8)];
            }
            if (t < 6) {
                gl_lds16(&sB[boff[2] + ko2], &lds[buf][1][lsl[2]]);
                gl_lds16(&sB[boff[3] + ko2], &lds[buf][1][lsl[3]]);
                gl_lds16(&sA[aoff[2] + ko2], &lds[buf][0][lsl[2]]);
            }
            __builtin_amdgcn_s_barrier();
            __builtin_amdgcn_s_setprio(1);
#pragma unroll
            for (int mt = 0; mt < 4; ++mt)
#pragma unroll
                for (int nt = 0; nt < 4; ++nt)
                    acc[4 + mt][nt] = __builtin_amdgcn_mfma_f32_16x16x32_bf16(af[mt], bfr[nt][0], acc[4 + mt][nt], 0, 0, 0);
            __builtin_amdgcn_s_setprio(0);
            __builtin_amdgcn_sched_barrier(0);
            __builtin_amdgcn_s_barrier();
            // A slots 1,3 (mh=1 rows) now fully consumed
        }
        // ---- tile end: finish stage of t+2, counted wait, publish t+1 ----
        if (t < 6) {
            gl_lds16(&sA[aoff[1] + ko2], &lds[buf][0][lsl[1]]);
            gl_lds16(&sA[aoff[3] + ko2], &lds[buf][0][lsl[3]]);
            asm volatile("s_waitcnt vmcnt(8)" ::: "memory");   // t+1 landed; t+2 in flight
            __builtin_amdgcn_s_barrier();
            asm volatile("" ::: "memory");
        } else if (t == 6) {
            asm volatile("s_waitcnt vmcnt(0)" ::: "memory");   // drain: tile 7 landed
            __builtin_amdgcn_s_barrier();
            asm volatile("" ::: "memory");
        }
    }

#pragma unroll
    for (int mt = 0; mt < 8; ++mt) {
#pragma unroll
        for (int nt = 0; nt < 4; ++nt) {
            int col = n0 + wn * 64 + nt * 16 + la;
#pragma unroll
            for (int rr = 0; rr < 4; ++rr) {
                int r = m0 + wm * 128 + mt * 16 + lg * 4 + rr;
                Co[(long)r * cstride + col] = f2bf(acc[mt][nt][rr]);
            }
        }
    }
}

// ---------------- windowed attention: 4 waves/block, KV interleaved [win][kv][1024] ----------------
// V consumed via per-wave LDS transpose: cooperative 16B row loads issued BEFORE QK^T
// (HBM latency hides under MFMAs), parked in a wave-private [64][70] slice (pad 70 ->
// column reads spread banks, conflict-free), PV reads 64 ds_read_u16.
__global__ __launch_bounds__(256) void attn_kernel(
    const u16* __restrict__ Q, const u16* __restrict__ KV, u16* __restrict__ O) {
    __shared__ u16 Vls[4][64][70];
    __shared__ u16 P[4][16 * 104];
    int bid = blockIdx.x;
    int wgid = (bid & 7) * 256 + (bid >> 3);  // grid 2048, XCD chunk swizzle
    int tid = threadIdx.x;
    int wid = tid >> 6;
    int lane = tid & 63;
    int win = wgid >> 1;
    int h = (wgid & 1) * 4 + wid;
    int la = lane & 15, lg = lane >> 4;
    u16* Pw = P[wid];
    const u16* Qb = Q + (long)win * 16 * 512 + h * 64;
    const u16* Kb = KV + (long)win * 64 * 1024 + h * 64;
    const u16* Vb = KV + (long)win * 64 * 1024 + 512 + h * 64;

    // V tile -> wave-private LDS slice (issue early; latency hides under QK^T)
    {
        int rsel = lane >> 3;          // 8 rows per iteration
        int dsel = (lane & 7) * 8;     // 8 lanes cover one 128B row
#pragma unroll
        for (int i = 0; i < 8; ++i) {
            int kv = i * 8 + rsel;
            s16x8 v = *(const s16x8*)&Vb[(long)kv * 1024 + dsel];
            *(s16x8*)&Vls[wid][kv][dsel] = v;
        }
    }

    s16x8 qf[2];
#pragma unroll
    for (int kk = 0; kk < 2; ++kk)
        qf[kk] = *(const s16x8*)&Qb[la * 512 + kk * 32 + lg * 8];

    const f32x4 z = {0.f, 0.f, 0.f, 0.f};
    f32x4 st[4];
#pragma unroll
    for (int rt = 0; rt < 4; ++rt) st[rt] = z;
#pragma unroll
    for (int rt = 0; rt < 4; ++rt)
#pragma unroll
        for (int kk = 0; kk < 2; ++kk) {
            s16x8 kf = *(const s16x8*)&Kb[(rt * 16 + la) * 1024 + kk * 32 + lg * 8];
            st[rt] = __builtin_amdgcn_mfma_f32_16x16x32_bf16(kf, qf[kk], st[rt], 0, 0, 0);
        }
    float mloc = -1e30f;
#pragma unroll
    for (int rt = 0; rt < 4; ++rt)
#pragma unroll
        for (int rr = 0; rr < 4; ++rr) {
            st[rt][rr] *= 0.125f;
            mloc = fmaxf(mloc, st[rt][rr]);
        }
    mloc = fmaxf(mloc, __shfl_xor(mloc, 16));
    mloc = fmaxf(mloc, __shfl_xor(mloc, 32));
    float p[4][4];
    float sloc = 0.f;
#pragma unroll
    for (int rt = 0; rt < 4; ++rt)
#pragma unroll
        for (int rr = 0; rr < 4; ++rr) {
            p[rt][rr] = __expf(st[rt][rr] - mloc);
            sloc += p[rt][rr];
        }
    sloc += __shfl_xor(sloc, 16);
    sloc += __shfl_xor(sloc, 32);
    float inv = 1.0f / sloc;
#pragma unroll
    for (int rt = 0; rt < 4; ++rt)
#pragma unroll
        for (int rr = 0; rr < 4; ++rr)
            Pw[la * 104 + rt * 16 + lg * 4 + rr] = f2bf(p[rt][rr] * inv);
    __syncthreads();

    f32x4 od[4];
#pragma unroll
    for (int dt = 0; dt < 4; ++dt) od[dt] = z;
#pragma unroll
    for (int kk2 = 0; kk2 < 2; ++kk2) {
        s16x8 pa = *(const s16x8*)&Pw[la * 104 + kk2 * 32 + lg * 8];
#pragma unroll
        for (int dt = 0; dt < 4; ++dt) {
            s16x8 vb;
#pragma unroll
            for (int j = 0; j < 8; ++j)
                vb[j] = (short)Vls[wid][kk2 * 32 + lg * 8 + j][dt * 16 + la];
            od[dt] = __builtin_amdgcn_mfma_f32_16x16x32_bf16(pa, vb, od[dt], 0, 0, 0);
        }
    }
    u16* Ob = O + (long)win * 16 * 512 + h * 64;
#pragma unroll
    for (int dt = 0; dt < 4; ++dt)
#pragma unroll
        for (int rr = 0; rr < 4; ++rr)
            Ob[(long)(lg * 4 + rr) * 512 + dt * 16 + la] = f2bf(od[dt][rr]);
}

__global__ void sentinel_kernel(float* out) {
    if (threadIdx.x == 0 && blockIdx.x == 0) out[0] = -12345.0f;
}

extern "C" void kernel_launch(void* const* d_in, const int* in_sizes, int n_in,
                              void* d_out, int out_size, void* d_ws, size_t ws_size,
                              hipStream_t stream) {
    const float* x   = (const float*)d_in[0];
    const float* ctx = (const float*)d_in[1];
    const float* Wq  = (const float*)d_in[2];
    const float* Wk  = (const float*)d_in[3];
    const float* Wv  = (const float*)d_in[4];
    const float* Wo  = (const float*)d_in[5];
    const float* bo  = (const float*)d_in[6];
    float* out = (float*)d_out;

    u16* wsb  = (u16*)d_ws;
    u16* WT   = wsb;                    // 4 * 512*512 (q, k, v, o transposed)
    u16* Aq   = WT + 4l * 262144;       // 16384*512
    u16* Actx = Aq + 8388608l;          // 65536*512
    u16* Qb   = Actx + 33554432l;       // 16384*512
    u16* KVb  = Qb + 8388608l;          // 65536*1024 (K cols 0..511, V cols 512..1023)
    u16* Ob   = KVb + 67108864l;        // 16384*512
    size_t need = (size_t)(126877696l) * 2;
    if (ws_size < need) {
        sentinel_kernel<<<1, 64, 0, stream>>>(out);
        return;
    }

    prep_kernel<<<12544, 256, 0, stream>>>(Wq, Wk, Wv, Wo, WT, x, Aq, ctx, Actx);
    gemmkvq_kernel<<<1152, 512, 0, stream>>>(Actx, WT + 262144l, Aq, WT, KVb, Qb);
    attn_kernel<<<2048, 256, 0, stream>>>(Qb, KVb, Ob);
    gemm128_kernel<1><<<512, 256, 0, stream>>>(Ob, WT + 3l * 262144, nullptr, out, bo);
}

// Round 14
// 188.004 us; speedup vs baseline: 1.0518x; 1.0313x over previous
//
#include <hip/hip_runtime.h>
#include <hip/hip_bf16.h>

typedef unsigned short u16;
typedef unsigned int u32;
typedef __attribute__((ext_vector_type(4))) float f32x4;
typedef __attribute__((ext_vector_type(4))) u16 u16x4;
typedef __attribute__((ext_vector_type(8))) u16 u16x8;
typedef __attribute__((ext_vector_type(8))) short s16x8;

__device__ __forceinline__ u16 f2bf(float f) {
    union { float f; u32 u; } v; v.f = f;
    u32 r = v.u + 0x7FFFu + ((v.u >> 16) & 1u);
    return (u16)(r >> 16);
}

__device__ __forceinline__ void gl_lds16(const u16* g, u16* l) {
    __builtin_amdgcn_global_load_lds(
        (const __attribute__((address_space(1))) unsigned int*)(const void*)g,
        (__attribute__((address_space(3))) unsigned int*)(void*)l, 16, 0, 0);
}

// ---------------- fused prep: permc (8192 blocks) + permx (4096) + wtrans (256) ----------------
__global__ __launch_bounds__(256) void prep_kernel(
    const float* __restrict__ w0, const float* __restrict__ w1,
    const float* __restrict__ w2, const float* __restrict__ w3, u16* __restrict__ WT,
    const float* __restrict__ x, u16* __restrict__ Aq,
    const float* __restrict__ ctx, u16* __restrict__ Actx) {
    __shared__ char smem[16640];
    int bid = blockIdx.x;
    int tid = threadIdx.x;
    if (bid < 8192) {
        // ---- permc: context -> Actx (65536 x 512 bf16), tiled transpose ----
        u16 (*t)[68] = (u16(*)[68])smem;
        int b2 = bid;
        int cb = b2 & 7; b2 >>= 3;
        int xb = b2 & 1; b2 >>= 1;
        int y  = b2 & 127; b2 >>= 7;
        int b  = b2;
        long ibase = ((long)(b * 512 + cb * 64) * 128 + y) * 128 + xb * 64;
#pragma unroll
        for (int p = 0; p < 4; ++p) {
            int task = p * 256 + tid;
            int cc = task >> 4, xl = (task & 15) * 4;
            float4 v = *(const float4*)&ctx[ibase + (long)cc * 16384 + xl];
            u16x4 o = {f2bf(v.x), f2bf(v.y), f2bf(v.z), f2bf(v.w)};
            *(u16x4*)&t[cc][xl] = o;
        }
        __syncthreads();
#pragma unroll
        for (int p = 0; p < 2; ++p) {
            int task = p * 256 + tid;
            int xx = task >> 3, j = task & 7;
            u16x8 o;
#pragma unroll
            for (int i = 0; i < 8; ++i) o[i] = t[j * 8 + i][xx];
            int xg = xb * 64 + xx;
            int row = b * 16384 + (y >> 3) * 1024 + (xg >> 3) * 64 + (y & 7) * 8 + (xg & 7);
            *(u16x8*)&Actx[(long)row * 512 + cb * 64 + j * 8] = o;
        }
    } else if (bid < 12288) {
        // ---- permx: x -> Aq (16384 x 512 bf16), tiled transpose ----
        u16 (*t)[36] = (u16(*)[36])smem;
        int b2 = bid - 8192;
        int cb = b2 & 7; b2 >>= 3;
        int y  = b2 & 31; b2 >>= 5;
        int tt = b2 & 3; b2 >>= 2;
        int b  = b2;
        long ibase = ((long)(b * 512 + cb * 64) * 4 + tt) * 1024 + y * 32;
#pragma unroll
        for (int p = 0; p < 2; ++p) {
            int task = p * 256 + tid;
            int cc = task >> 3, xl = (task & 7) * 4;
            float4 v = *(const float4*)&x[ibase + (long)cc * 4096 + xl];
            u16x4 o = {f2bf(v.x), f2bf(v.y), f2bf(v.z), f2bf(v.w)};
            *(u16x4*)&t[cc][xl] = o;
        }
        __syncthreads();
        {
            int xx = tid >> 3, j = tid & 7;
            u16x8 o;
#pragma unroll
            for (int i = 0; i < 8; ++i) o[i] = t[j * 8 + i][xx];
            int row = b * 4096 + (y >> 1) * 256 + (xx >> 1) * 16 + tt * 4 + (y & 1) * 2 + (xx & 1);
            *(u16x8*)&Aq[(long)row * 512 + cb * 64 + j * 8] = o;
        }
    } else {
        // ---- wtrans: Wt[j][c] = W[c][j], f32 -> bf16 ----
        float (*t)[65] = (float(*)[65])smem;
        int b2 = bid - 12288;
        int wsel = b2 >> 6;
        int tile = b2 & 63;
        int j0 = (tile >> 3) * 64, c0 = (tile & 7) * 64;
        const float* src = wsel == 0 ? w0 : wsel == 1 ? w1 : wsel == 2 ? w2 : w3;
        u16* out = WT + (long)wsel * 512 * 512;
        int tj = tid & 63;
        int ti = tid >> 6;
#pragma unroll
        for (int p = 0; p < 16; ++p) {
            int row = p * 4 + ti;
            t[row][tj] = src[(long)(c0 + row) * 512 + j0 + tj];
        }
        __syncthreads();
#pragma unroll
        for (int p = 0; p < 16; ++p) {
            int jl = p * 4 + ti;
            out[(long)(j0 + jl) * 512 + c0 + tj] = f2bf(t[tj][jl]);
        }
    }
}

// ---------------- 128x128-tile bf16 GEMM (final proj), counted-vmcnt schedule ----------------
template <int FINAL>
__global__ __launch_bounds__(256, 2) void gemm128_kernel(
    const u16* __restrict__ A, const u16* __restrict__ Bt,
    u16* __restrict__ Cb, float* __restrict__ Cf, const float* __restrict__ bias) {
    __shared__ u16 As[2][8192];
    __shared__ u16 Bs[2][8192];
    int tid = threadIdx.x;
    int lane = tid & 63;
    int w = tid >> 6;
    int wm = w >> 1, wn = w & 1;
    int bid = blockIdx.x;
    int wg = (bid & 7) * 64 + (bid >> 3);   // grid 512, XCD chunk swizzle
    int m0 = (wg >> 2) * 128;
    int n0 = (wg & 3) * 128;

    const f32x4 z = {0.f, 0.f, 0.f, 0.f};
    f32x4 acc[4][4];
#pragma unroll
    for (int i = 0; i < 4; ++i)
#pragma unroll
        for (int j = 0; j < 4; ++j) acc[i][j] = z;

    int aoff[4], boff[4], lb[4];
#pragma unroll
    for (int i = 0; i < 4; ++i) {
        int s = i * 256 + tid;
        int row = s >> 3;
        int cb = (s & 7) ^ (row & 7);
        aoff[i] = (m0 + row) * 512 + cb * 8;
        boff[i] = (n0 + row) * 512 + cb * 8;
        lb[i] = (i * 256 + w * 64) * 8;
    }
    int la = lane & 15, lg = lane >> 4;

    // prologue: stage K-tiles 0 (buf0) and 1 (buf1)
#pragma unroll
    for (int i = 0; i < 4; ++i) {
        gl_lds16(&A[aoff[i]], &As[0][lb[i]]);
        gl_lds16(&Bt[boff[i]], &Bs[0][lb[i]]);
    }
#pragma unroll
    for (int i = 0; i < 4; ++i) {
        gl_lds16(&A[aoff[i] + 64], &As[1][lb[i]]);
        gl_lds16(&Bt[boff[i] + 64], &Bs[1][lb[i]]);
    }
    asm volatile("s_waitcnt vmcnt(8)" ::: "memory");   // tile0 landed; tile1 in flight
    __builtin_amdgcn_s_barrier();
    asm volatile("" ::: "memory");

#pragma unroll
    for (int t = 0; t < 8; ++t) {
        int buf = t & 1;
        const u16* Ab = As[buf];
        const u16* Bb = Bs[buf];
#pragma unroll
        for (int kk = 0; kk < 2; ++kk) {
            int cb = kk * 4 + lg;
            s16x8 af[4], bfr[4];
#pragma unroll
            for (int mt = 0; mt < 4; ++mt) {
                int r = wm * 64 + mt * 16 + la;
                af[mt] = *(const s16x8*)&Ab[r * 64 + ((cb ^ (r & 7)) * 8)];
            }
#pragma unroll
            for (int nt = 0; nt < 4; ++nt) {
                int c = wn * 64 + nt * 16 + la;
                bfr[nt] = *(const s16x8*)&Bb[c * 64 + ((cb ^ (c & 7)) * 8)];
            }
            __builtin_amdgcn_s_setprio(1);
#pragma unroll
            for (int mt = 0; mt < 4; ++mt)
#pragma unroll
                for (int nt = 0; nt < 4; ++nt)
                    acc[mt][nt] = __builtin_amdgcn_mfma_f32_16x16x32_bf16(af[mt], bfr[nt], acc[mt][nt], 0, 0, 0);
            __builtin_amdgcn_s_setprio(0);
        }
        if (t < 6) {
            asm volatile("" ::: "memory");
            __builtin_amdgcn_s_barrier();              // all waves done reading buf t&1
            int ko2 = (t + 2) * 64;
#pragma unroll
            for (int i = 0; i < 4; ++i) {
                gl_lds16(&A[aoff[i] + ko2], &As[buf][lb[i]]);
                gl_lds16(&Bt[boff[i] + ko2], &Bs[buf][lb[i]]);
            }
            asm volatile("s_waitcnt vmcnt(8)" ::: "memory");  // t+1 landed; t+2 in flight
            __builtin_amdgcn_s_barrier();              // publish tile t+1
            asm volatile("" ::: "memory");
        } else if (t == 6) {
            asm volatile("s_waitcnt vmcnt(0)" ::: "memory");  // drain: tile 7 landed
            __builtin_amdgcn_s_barrier();
            asm volatile("" ::: "memory");
        }
    }

#pragma unroll
    for (int mt = 0; mt < 4; ++mt) {
#pragma unroll
        for (int nt = 0; nt < 4; ++nt) {
            int col = n0 + wn * 64 + nt * 16 + la;
#pragma unroll
            for (int rr = 0; rr < 4; ++rr) {
                int r = m0 + wm * 64 + mt * 16 + lg * 4 + rr;
                float v = acc[mt][nt][rr];
                if (FINAL) {
                    int bb = r >> 12, hg = (r >> 8) & 15, wgx = (r >> 4) & 15;
                    int tt = (r >> 2) & 3, rr0 = (r >> 1) & 1, cc0 = r & 1;
                    int tok = bb * 4096 + tt * 1024 + (hg * 2 + rr0) * 32 + wgx * 2 + cc0;
                    Cf[(long)tok * 512 + col] = v + bias[col];
                } else {
                    Cb[(long)r * 512 + col] = f2bf(v);
                }
            }
        }
    }
}

// ---------------- fused K+V + Q GEMM ----------------
// Grid 1280 = 1024 KV-blocks (256^2 tiles, 4-phase schedule, r13-verbatim) + 256 Q-blocks
// (256x128 tiles, HALF duration).  Per XCD: 128 KV (4 full rounds) + 32 Q = exactly 1
// half-size block per CU -> the tail is one uniform half-round on ALL CUs, fixing r13's
// half-idle full-round tail (16 full Q-blocks on 32 CUs).
__global__ __launch_bounds__(512, 2) void gemmkvq_kernel(
    const u16* __restrict__ Actx, const u16* __restrict__ Bkv,
    const u16* __restrict__ Aq, const u16* __restrict__ WTq,
    u16* __restrict__ CKV, u16* __restrict__ CQ) {
    __shared__ u16 lds[2][2][16384];   // [buf][A/B][256 rows x 64]
    int tid = threadIdx.x;
    int lane = tid & 63;
    int w = tid >> 6;                  // 0..7
    int la = lane & 15, lg = lane >> 4;
    int bid = blockIdx.x;
    int xcd = bid & 7;
    int loc = bid >> 3;                // 0..159

    const f32x4 z = {0.f, 0.f, 0.f, 0.f};

    if (loc < 128) {
        // ================= KV path: r13-verbatim (wg = xcd*128 + loc) =================
        int wm = w >> 2, wn = w & 3;
        int wg = xcd * 128 + loc;
        int m0 = (wg >> 2) * 256;
        int n0 = (wg & 3) * 256;

        f32x4 acc[8][4];
#pragma unroll
        for (int i = 0; i < 8; ++i)
#pragma unroll
            for (int j = 0; j < 4; ++j) acc[i][j] = z;

        int aoff[4], boff[4], lsl[4];
#pragma unroll
        for (int i = 0; i < 4; ++i) {
            int s = i * 512 + tid;
            int row = s >> 3;
            int cb = (s & 7) ^ (row & 7);
            aoff[i] = (m0 + row) * 512 + cb * 8;
            boff[i] = (n0 + row) * 512 + cb * 8;
            lsl[i] = (i * 512 + w * 64) * 8;
        }

        s16x8 bfr[4][2];

#pragma unroll
        for (int i = 0; i < 4; ++i) {
            gl_lds16(&Actx[aoff[i]], &lds[0][0][lsl[i]]);
            gl_lds16(&Bkv[boff[i]], &lds[0][1][lsl[i]]);
        }
#pragma unroll
        for (int i = 0; i < 4; ++i) {
            gl_lds16(&Actx[aoff[i] + 64], &lds[1][0][lsl[i]]);
            gl_lds16(&Bkv[boff[i] + 64], &lds[1][1][lsl[i]]);
        }
        asm volatile("s_waitcnt vmcnt(8)" ::: "memory");
        __builtin_amdgcn_s_barrier();
        asm volatile("" ::: "memory");

#pragma unroll
        for (int t = 0; t < 8; ++t) {
            int buf = t & 1;
            const u16* Ab = lds[buf][0];
            const u16* Bb = lds[buf][1];
            int ko2 = (t + 2) * 64;

            // ---- P1: (mh=0, kk=0) ----
            {
                int cb = lg;
                s16x8 af[4];
#pragma unroll
                for (int mt = 0; mt < 4; ++mt) {
                    int r = wm * 128 + mt * 16 + la;
                    af[mt] = *(const s16x8*)&Ab[r * 64 + ((cb ^ (r & 7)) * 8)];
                }
#pragma unroll
                for (int nt = 0; nt < 4; ++nt) {
                    int c = wn * 64 + nt * 16 + la;
                    bfr[nt][0] = *(const s16x8*)&Bb[c * 64 + ((cb ^ (c & 7)) * 8)];
                }
                __builtin_amdgcn_s_barrier();
                __builtin_amdgcn_s_setprio(1);
#pragma unroll
                for (int mt = 0; mt < 4; ++mt)
#pragma unroll
                    for (int nt = 0; nt < 4; ++nt)
                        acc[mt][nt] = __builtin_amdgcn_mfma_f32_16x16x32_bf16(af[mt], bfr[nt][0], acc[mt][nt], 0, 0, 0);
                __builtin_amdgcn_s_setprio(0);
                __builtin_amdgcn_sched_barrier(0);
                __builtin_amdgcn_s_barrier();
            }
            // ---- P2: (mh=0, kk=1) ----
            {
                int cb = 4 + lg;
                s16x8 af[4];
#pragma unroll
                for (int mt = 0; mt < 4; ++mt) {
                    int r = wm * 128 + mt * 16 + la;
                    af[mt] = *(const s16x8*)&Ab[r * 64 + ((cb ^ (r & 7)) * 8)];
                }
#pragma unroll
                for (int nt = 0; nt < 4; ++nt) {
                    int c = wn * 64 + nt * 16 + la;
                    bfr[nt][1] = *(const s16x8*)&Bb[c * 64 + ((cb ^ (c & 7)) * 8)];
                }
                __builtin_amdgcn_s_barrier();
                __builtin_amdgcn_s_setprio(1);
#pragma unroll
                for (int mt = 0; mt < 4; ++mt)
#pragma unroll
                    for (int nt = 0; nt < 4; ++nt)
                        acc[mt][nt] = __builtin_amdgcn_mfma_f32_16x16x32_bf16(af[mt], bfr[nt][1], acc[mt][nt], 0, 0, 0);
                __builtin_amdgcn_s_setprio(0);
                __builtin_amdgcn_sched_barrier(0);
                __builtin_amdgcn_s_barrier();
            }
            // ---- P3: (mh=1, kk=1); stage B 0,1 + A 0 of t+2 ----
            {
                int cb = 4 + lg;
                s16x8 af[4];
#pragma unroll
                for (int mt = 0; mt < 4; ++mt) {
                    int r = wm * 128 + 64 + mt * 16 + la;
                    af[mt] = *(const s16x8*)&Ab[r * 64 + ((cb ^ (r & 7)) * 8)];
                }
                if (t < 6) {
                    gl_lds16(&Bkv[boff[0] + ko2], &lds[buf][1][lsl[0]]);
                    gl_lds16(&Bkv[boff[1] + ko2], &lds[buf][1][lsl[1]]);
                    gl_lds16(&Actx[aoff[0] + ko2], &lds[buf][0][lsl[0]]);
                }
                __builtin_amdgcn_s_barrier();
                __builtin_amdgcn_s_setprio(1);
#pragma unroll
                for (int mt = 0; mt < 4; ++mt)
#pragma unroll
                    for (int nt = 0; nt < 4; ++nt)
                        acc[4 + mt][nt] = __builtin_amdgcn_mfma_f32_16x16x32_bf16(af[mt], bfr[nt][1], acc[4 + mt][nt], 0, 0, 0);
                __builtin_amdgcn_s_setprio(0);
                __builtin_amdgcn_sched_barrier(0);
                __builtin_amdgcn_s_barrier();
            }
            // ---- P4: (mh=1, kk=0); stage B 2,3 + A 2 of t+2 ----
            {
                int cb = lg;
                s16x8 af[4];
#pragma unroll
                for (int mt = 0; mt < 4; ++mt) {
                    int r = wm * 128 + 64 + mt * 16 + la;
                    af[mt] = *(const s16x8*)&Ab[r * 64 + ((cb ^ (r & 7)) * 8)];
                }
                if (t < 6) {
                    gl_lds16(&Bkv[boff[2] + ko2], &lds[buf][1][lsl[2]]);
                    gl_lds16(&Bkv[boff[3] + ko2], &lds[buf][1][lsl[3]]);
                    gl_lds16(&Actx[aoff[2] + ko2], &lds[buf][0][lsl[2]]);
                }
                __builtin_amdgcn_s_barrier();
                __builtin_amdgcn_s_setprio(1);
#pragma unroll
                for (int mt = 0; mt < 4; ++mt)
#pragma unroll
                    for (int nt = 0; nt < 4; ++nt)
                        acc[4 + mt][nt] = __builtin_amdgcn_mfma_f32_16x16x32_bf16(af[mt], bfr[nt][0], acc[4 + mt][nt], 0, 0, 0);
                __builtin_amdgcn_s_setprio(0);
                __builtin_amdgcn_sched_barrier(0);
                __builtin_amdgcn_s_barrier();
            }
            // ---- tile end ----
            if (t < 6) {
                gl_lds16(&Actx[aoff[1] + ko2], &lds[buf][0][lsl[1]]);
                gl_lds16(&Actx[aoff[3] + ko2], &lds[buf][0][lsl[3]]);
                asm volatile("s_waitcnt vmcnt(8)" ::: "memory");
                __builtin_amdgcn_s_barrier();
                asm volatile("" ::: "memory");
            } else if (t == 6) {
                asm volatile("s_waitcnt vmcnt(0)" ::: "memory");
                __builtin_amdgcn_s_barrier();
                asm volatile("" ::: "memory");
            }
        }

#pragma unroll
        for (int mt = 0; mt < 8; ++mt) {
#pragma unroll
            for (int nt = 0; nt < 4; ++nt) {
                int col = n0 + wn * 64 + nt * 16 + la;
#pragma unroll
                for (int rr = 0; rr < 4; ++rr) {
                    int r = m0 + wm * 128 + mt * 16 + lg * 4 + rr;
                    CKV[(long)r * 1024 + col] = f2bf(acc[mt][nt][rr]);
                }
            }
        }
        return;
    }

    // ================= Q path: 256x128 tile, 8 waves (4m x 2n), 2-phase vmcnt(6) =================
    {
        int wm = w >> 1, wn = w & 1;
        int q = xcd * 32 + (loc - 128);    // 0..255
        int m0 = (q >> 2) * 256;
        int n0 = (q & 3) * 128;

        f32x4 acc[4][4];
#pragma unroll
        for (int i = 0; i < 4; ++i)
#pragma unroll
            for (int j = 0; j < 4; ++j) acc[i][j] = z;

        int aoff[4], lsa[4], boff[2], lsb[2];
#pragma unroll
        for (int i = 0; i < 4; ++i) {
            int s = i * 512 + tid;
            int row = s >> 3;
            int cb = (s & 7) ^ (row & 7);
            aoff[i] = (m0 + row) * 512 + cb * 8;
            lsa[i] = (i * 512 + w * 64) * 8;
        }
#pragma unroll
        for (int i = 0; i < 2; ++i) {
            int s = i * 512 + tid;
            int row = s >> 3;
            int cb = (s & 7) ^ (row & 7);
            boff[i] = (n0 + row) * 512 + cb * 8;
            lsb[i] = (i * 512 + w * 64) * 8;
        }

        // prologue: stage tiles 0 (buf0) and 1 (buf1): 6 loads each
#pragma unroll
        for (int i = 0; i < 4; ++i) gl_lds16(&Aq[aoff[i]], &lds[0][0][lsa[i]]);
#pragma unroll
        for (int i = 0; i < 2; ++i) gl_lds16(&WTq[boff[i]], &lds[0][1][lsb[i]]);
#pragma unroll
        for (int i = 0; i < 4; ++i) gl_lds16(&Aq[aoff[i] + 64], &lds[1][0][lsa[i]]);
#pragma unroll
        for (int i = 0; i < 2; ++i) gl_lds16(&WTq[boff[i] + 64], &lds[1][1][lsb[i]]);
        asm volatile("s_waitcnt vmcnt(6)" ::: "memory");   // tile0 landed; tile1 in flight
        __builtin_amdgcn_s_barrier();
        asm volatile("" ::: "memory");

#pragma unroll
        for (int t = 0; t < 8; ++t) {
            int buf = t & 1;
            const u16* Ab = lds[buf][0];
            const u16* Bb = lds[buf][1];
#pragma unroll
            for (int kk = 0; kk < 2; ++kk) {
                int cb = kk * 4 + lg;
                s16x8 af[4], bfr[4];
#pragma unroll
                for (int mt = 0; mt < 4; ++mt) {
                    int r = wm * 64 + mt * 16 + la;
                    af[mt] = *(const s16x8*)&Ab[r * 64 + ((cb ^ (r & 7)) * 8)];
                }
#pragma unroll
                for (int nt = 0; nt < 4; ++nt) {
                    int c = wn * 64 + nt * 16 + la;
                    bfr[nt] = *(const s16x8*)&Bb[c * 64 + ((cb ^ (c & 7)) * 8)];
                }
                __builtin_amdgcn_s_setprio(1);
#pragma unroll
                for (int mt = 0; mt < 4; ++mt)
#pragma unroll
                    for (int nt = 0; nt < 4; ++nt)
                        acc[mt][nt] = __builtin_amdgcn_mfma_f32_16x16x32_bf16(af[mt], bfr[nt], acc[mt][nt], 0, 0, 0);
                __builtin_amdgcn_s_setprio(0);
            }
            if (t < 6) {
                asm volatile("" ::: "memory");
                __builtin_amdgcn_s_barrier();          // all waves done reading buf t&1
                int ko2 = (t + 2) * 64;
#pragma unroll
                for (int i = 0; i < 4; ++i) gl_lds16(&Aq[aoff[i] + ko2], &lds[buf][0][lsa[i]]);
#pragma unroll
                for (int i = 0; i < 2; ++i) gl_lds16(&WTq[boff[i] + ko2], &lds[buf][1][lsb[i]]);
                asm volatile("s_waitcnt vmcnt(6)" ::: "memory");  // t+1 landed; t+2 in flight
                __builtin_amdgcn_s_barrier();          // publish tile t+1
                asm volatile("" ::: "memory");
            } else if (t == 6) {
                asm volatile("s_waitcnt vmcnt(0)" ::: "memory");  // drain: tile 7 landed
                __builtin_amdgcn_s_barrier();
                asm volatile("" ::: "memory");
            }
        }

#pragma unroll
        for (int mt = 0; mt < 4; ++mt) {
#pragma unroll
            for (int nt = 0; nt < 4; ++nt) {
                int col = n0 + wn * 64 + nt * 16 + la;
#pragma unroll
                for (int rr = 0; rr < 4; ++rr) {
                    int r = m0 + wm * 64 + mt * 16 + lg * 4 + rr;
                    CQ[(long)r * 512 + col] = f2bf(acc[mt][nt][rr]);
                }
            }
        }
    }
}

// ---------------- windowed attention: 4 waves/block, KV interleaved [win][kv][1024] ----------------
// V consumed via per-wave LDS transpose: cooperative 16B row loads issued BEFORE QK^T
// (HBM latency hides under MFMAs), parked in a wave-private [64][70] slice (pad 70 ->
// column reads spread banks, conflict-free), PV reads 64 ds_read_u16.
__global__ __launch_bounds__(256) void attn_kernel(
    const u16* __restrict__ Q, const u16* __restrict__ KV, u16* __restrict__ O) {
    __shared__ u16 Vls[4][64][70];
    __shared__ u16 P[4][16 * 104];
    int bid = blockIdx.x;
    int wgid = (bid & 7) * 256 + (bid >> 3);  // grid 2048, XCD chunk swizzle
    int tid = threadIdx.x;
    int wid = tid >> 6;
    int lane = tid & 63;
    int win = wgid >> 1;
    int h = (wgid & 1) * 4 + wid;
    int la = lane & 15, lg = lane >> 4;
    u16* Pw = P[wid];
    const u16* Qb = Q + (long)win * 16 * 512 + h * 64;
    const u16* Kb = KV + (long)win * 64 * 1024 + h * 64;
    const u16* Vb = KV + (long)win * 64 * 1024 + 512 + h * 64;

    // V tile -> wave-private LDS slice (issue early; latency hides under QK^T)
    {
        int rsel = lane >> 3;          // 8 rows per iteration
        int dsel = (lane & 7) * 8;     // 8 lanes cover one 128B row
#pragma unroll
        for (int i = 0; i < 8; ++i) {
            int kv = i * 8 + rsel;
            s16x8 v = *(const s16x8*)&Vb[(long)kv * 1024 + dsel];
            *(s16x8*)&Vls[wid][kv][dsel] = v;
        }
    }

    s16x8 qf[2];
#pragma unroll
    for (int kk = 0; kk < 2; ++kk)
        qf[kk] = *(const s16x8*)&Qb[la * 512 + kk * 32 + lg * 8];

    const f32x4 z = {0.f, 0.f, 0.f, 0.f};
    f32x4 st[4];
#pragma unroll
    for (int rt = 0; rt < 4; ++rt) st[rt] = z;
#pragma unroll
    for (int rt = 0; rt < 4; ++rt)
#pragma unroll
        for (int kk = 0; kk < 2; ++kk) {
            s16x8 kf = *(const s16x8*)&Kb[(rt * 16 + la) * 1024 + kk * 32 + lg * 8];
            st[rt] = __builtin_amdgcn_mfma_f32_16x16x32_bf16(kf, qf[kk], st[rt], 0, 0, 0);
        }
    float mloc = -1e30f;
#pragma unroll
    for (int rt = 0; rt < 4; ++rt)
#pragma unroll
        for (int rr = 0; rr < 4; ++rr) {
            st[rt][rr] *= 0.125f;
            mloc = fmaxf(mloc, st[rt][rr]);
        }
    mloc = fmaxf(mloc, __shfl_xor(mloc, 16));
    mloc = fmaxf(mloc, __shfl_xor(mloc, 32));
    float p[4][4];
    float sloc = 0.f;
#pragma unroll
    for (int rt = 0; rt < 4; ++rt)
#pragma unroll
        for (int rr = 0; rr < 4; ++rr) {
            p[rt][rr] = __expf(st[rt][rr] - mloc);
            sloc += p[rt][rr];
        }
    sloc += __shfl_xor(sloc, 16);
    sloc += __shfl_xor(sloc, 32);
    float inv = 1.0f / sloc;
#pragma unroll
    for (int rt = 0; rt < 4; ++rt)
#pragma unroll
        for (int rr = 0; rr < 4; ++rr)
            Pw[la * 104 + rt * 16 + lg * 4 + rr] = f2bf(p[rt][rr] * inv);
    __syncthreads();

    f32x4 od[4];
#pragma unroll
    for (int dt = 0; dt < 4; ++dt) od[dt] = z;
#pragma unroll
    for (int kk2 = 0; kk2 < 2; ++kk2) {
        s16x8 pa = *(const s16x8*)&Pw[la * 104 + kk2 * 32 + lg * 8];
#pragma unroll
        for (int dt = 0; dt < 4; ++dt) {
            s16x8 vb;
#pragma unroll
            for (int j = 0; j < 8; ++j)
                vb[j] = (short)Vls[wid][kk2 * 32 + lg * 8 + j][dt * 16 + la];
            od[dt] = __builtin_amdgcn_mfma_f32_16x16x32_bf16(pa, vb, od[dt], 0, 0, 0);
        }
    }
    u16* Ob = O + (long)win * 16 * 512 + h * 64;
#pragma unroll
    for (int dt = 0; dt < 4; ++dt)
#pragma unroll
        for (int rr = 0; rr < 4; ++rr)
            Ob[(long)(lg * 4 + rr) * 512 + dt * 16 + la] = f2bf(od[dt][rr]);
}

__global__ void sentinel_kernel(float* out) {
    if (threadIdx.x == 0 && blockIdx.x == 0) out[0] = -12345.0f;
}

extern "C" void kernel_launch(void* const* d_in, const int* in_sizes, int n_in,
                              void* d_out, int out_size, void* d_ws, size_t ws_size,
                              hipStream_t stream) {
    const float* x   = (const float*)d_in[0];
    const float* ctx = (const float*)d_in[1];
    const float* Wq  = (const float*)d_in[2];
    const float* Wk  = (const float*)d_in[3];
    const float* Wv  = (const float*)d_in[4];
    const float* Wo  = (const float*)d_in[5];
    const float* bo  = (const float*)d_in[6];
    float* out = (float*)d_out;

    u16* wsb  = (u16*)d_ws;
    u16* WT   = wsb;                    // 4 * 512*512 (q, k, v, o transposed)
    u16* Aq   = WT + 4l * 262144;       // 16384*512
    u16* Actx = Aq + 8388608l;          // 65536*512
    u16* Qb   = Actx + 33554432l;       // 16384*512
    u16* KVb  = Qb + 8388608l;          // 65536*1024 (K cols 0..511, V cols 512..1023)
    u16* Ob   = KVb + 67108864l;        // 16384*512
    size_t need = (size_t)(126877696l) * 2;
    if (ws_size < need) {
        sentinel_kernel<<<1, 64, 0, stream>>>(out);
        return;
    }

    prep_kernel<<<12544, 256, 0, stream>>>(Wq, Wk, Wv, Wo, WT, x, Aq, ctx, Actx);
    gemmkvq_kernel<<<1280, 512, 0, stream>>>(Actx, WT + 262144l, Aq, WT, KVb, Qb);
    attn_kernel<<<2048, 256, 0, stream>>>(Qb, KVb, Ob);
    gemm128_kernel<1><<<512, 256, 0, stream>>>(Ob, WT + 3l * 262144, nullptr, out, bo);
}